// Round 11
// baseline (63.225 us; speedup 1.0000x reference)
//
#include <hip/hip_runtime.h>
#include <math.h>

#define BATCH 256
#define FEAT 128
#define CAP 100000
#define CAPP 100096         // padded to 16 (NBLK2*128)
#define ROWF 168
#define K 5
#define NBLK2 782           // blocks of 128 keys; 782*128 = 100096
#define NKB 6256            // key blocks in prep (16 keys each)
#define NCHK 6256           // 16-key chunks; CAP%16==0 -> chunks all-real or all-pad
#define SCPT 13             // ceil(NCHK/512)
#define MAXSEL 48
#define MARGIN 0.008f

// out layout (floats): retrieved [0,215040) | top_sims | valid_mask | top_idx
#define OUT_SIMS 215040
#define OUT_MASK 216320
#define OUT_IDX  217600

// ws layout (float units)
#define WS_SCALE 0          // 100096 f32: decay/||k|| (0 for pad keys)
#define WS_QF    100096     // 4096 uint4 = bf16 B-fragments
#define WS_TMAX  116480     // 256*6256 f32 chunk maxima

typedef __attribute__((ext_vector_type(8))) short short8;
typedef __attribute__((ext_vector_type(4))) float f32x4;

#define BET(vs,vi,ss,ii) ((vs) > (ss) || ((vs) == (ss) && (vi) < (ii)))

__device__ __forceinline__ unsigned short f2bf(float f) {
  unsigned u = __float_as_uint(f);
  u += 0x7fffu + ((u >> 16) & 1u);     // RNE (proven R4-R10)
  return (unsigned short)(u >> 16);
}
__device__ __forceinline__ unsigned pack2(float a, float b) {
  return (unsigned)f2bf(a) | ((unsigned)f2bf(b) << 16);
}

// sorted-5 insert, explicit (value desc, idx asc) tie-break
__device__ __forceinline__ void ins_cmp(float v, int k, float (&s)[5], int (&i)[5]) {
  if (BET(v,k,s[4],i[4])) {
    if (BET(v,k,s[3],i[3])) { s[4]=s[3]; i[4]=i[3];
      if (BET(v,k,s[2],i[2])) { s[3]=s[2]; i[3]=i[2];
        if (BET(v,k,s[1],i[1])) { s[2]=s[1]; i[2]=i[1];
          if (BET(v,k,s[0],i[0])) { s[1]=s[0]; i[1]=i[0]; s[0]=v; i[0]=k; }
          else { s[1]=v; i[1]=k; } }
        else { s[2]=v; i[2]=k; } }
      else { s[3]=v; i[3]=k; } }
    else { s[4]=v; i[4]=k; }
  }
}

// grid 16+NKB, block 256 (16 rows x 16 dim-slices).
// blocks 0..15: bf16 B-fragments for 16 queries each.
// blocks 16.. : scale[key] = 0.995^age / max(||k||,eps) for 16 keys each (pad->0).
__global__ __launch_bounds__(256) void prep(
    const float* __restrict__ query, const float* __restrict__ keys,
    const int* __restrict__ ts, const int* __restrict__ gstep,
    uint4* __restrict__ qF, float* __restrict__ scale) {
  int b = blockIdx.x, tid = threadIdx.x;
  int rid = tid >> 4, dp = tid & 15;
  if (b < 16) {
    int q_ = b*16 + rid;
    const float4* src = reinterpret_cast<const float4*>(query + (size_t)q_*FEAT + dp*8);
    float4 v0 = src[0], v1 = src[1];
    float ss = v0.x*v0.x + v0.y*v0.y + v0.z*v0.z + v0.w*v0.w
             + v1.x*v1.x + v1.y*v1.y + v1.z*v1.z + v1.w*v1.w;
    ss += __shfl_xor(ss,1); ss += __shfl_xor(ss,2);
    ss += __shfl_xor(ss,4); ss += __shfl_xor(ss,8);
    float inv = 1.0f / fmaxf(sqrtf(ss), 1e-12f);
    v0.x*=inv; v0.y*=inv; v0.z*=inv; v0.w*=inv;
    v1.x*=inv; v1.y*=inv; v1.z*=inv; v1.w*=inv;
    uint4 pk;
    pk.x = pack2(v0.x,v0.y); pk.y = pack2(v0.z,v0.w);
    pk.z = pack2(v1.x,v1.y); pk.w = pack2(v1.z,v1.w);
    int s_ = dp >> 2, lg = dp & 3;
    qF[(b*4 + s_)*64 + lg*16 + rid] = pk;
  } else {
    int key = (b-16)*16 + rid;
    int gk = key < CAP ? key : CAP-1;
    const float4* kp = reinterpret_cast<const float4*>(keys + (size_t)gk*FEAT + dp*8);
    float4 v0 = kp[0], v1 = kp[1];
    float ss = v0.x*v0.x + v0.y*v0.y + v0.z*v0.z + v0.w*v0.w
             + v1.x*v1.x + v1.y*v1.y + v1.z*v1.z + v1.w*v1.w;
    ss += __shfl_xor(ss,1); ss += __shfl_xor(ss,2);
    ss += __shfl_xor(ss,4); ss += __shfl_xor(ss,8);
    if (dp == 0) {
      float scl = 0.0f;
      if (key < CAP) {
        float age = (float)(gstep[0] - ts[key]);
        scl = exp2f(age * -0.00723157f) / fmaxf(sqrtf(ss), 1e-12f);  // approx only
      }
      scale[key] = scl;
    }
  }
}

// grid NBLK2 (128 keys/block), block 512 (8 waves; wave w owns q-groups 2w,2w+1).
// Branchless staging of RAW bf16 keys (no per-key math; scale applied in
// epilogue from precomputed table), MFMA, per-16-key-tile scaled maxima.
__global__ __launch_bounds__(512, 4) void gemm_max3(
    const float* __restrict__ keys, const float* __restrict__ scale,
    const uint4* __restrict__ qF, float* __restrict__ tmax) {
  __shared__ uint4 lds_kf[32*66];      // 8 tiles x 4 slabs, stride 66 (33 KB)
  int tid = threadIdx.x;
  int w = tid >> 6, lane = tid & 63;
  int blk = blockIdx.x;
  int kbase = blk * 128;

  short8 qf0[4], qf1[4];
  #pragma unroll
  for (int s_ = 0; s_ < 4; ++s_) {
    qf0[s_] = __builtin_bit_cast(short8, qF[((2*w  )*4 + s_)*64 + lane]);
    qf1[s_] = __builtin_bit_cast(short8, qF[((2*w+1)*4 + s_)*64 + lane]);
  }

  // stage: branchless (clamped addr; pad keys neutralized by scale=0)
  int dp = tid & 15;
  #pragma unroll
  for (int it = 0; it < 4; ++it) {
    int kl = it*32 + (tid >> 4);       // local key 0..127
    int gk = kbase + kl;
    gk = gk < CAP ? gk : CAP-1;
    const float4* kp = reinterpret_cast<const float4*>(keys + (size_t)gk*FEAT + dp*8);
    float4 v0 = kp[0], v1 = kp[1];
    uint4 pk;
    pk.x = pack2(v0.x, v0.y); pk.y = pack2(v0.z, v0.w);
    pk.z = pack2(v1.x, v1.y); pk.w = pack2(v1.z, v1.w);
    int slab = (kl >> 4)*4 + (dp >> 2);
    int slot = (dp & 3)*16 + (kl & 15);
    lds_kf[slab*66 + slot] = pk;
  }
  __syncthreads();

  float tm0[8], tm1[8];
  #pragma unroll
  for (int t = 0; t < 8; ++t) {
    f32x4 acc0 = {0.f,0.f,0.f,0.f}, acc1 = {0.f,0.f,0.f,0.f};
    #pragma unroll
    for (int s_ = 0; s_ < 4; ++s_) {
      short8 a = __builtin_bit_cast(short8, lds_kf[(t*4 + s_)*66 + lane]);
      acc0 = __builtin_amdgcn_mfma_f32_16x16x32_bf16(a, qf0[s_], acc0, 0,0,0);
      acc1 = __builtin_amdgcn_mfma_f32_16x16x32_bf16(a, qf1[s_], acc1, 0,0,0);
    }
    // C/D: col=lane&15 (query), row=(lane>>4)*4+r (key).
    // scale broadcast-load (16 lanes same addr); pad keys scale=0 -> sims 0.
    int kb = kbase + t*16 + (lane>>4)*4;
    float4 sc = *reinterpret_cast<const float4*>(&scale[kb]);
    float m0 = fmaxf(fmaxf(acc0[0]*sc.x, acc0[1]*sc.y),
                     fmaxf(acc0[2]*sc.z, acc0[3]*sc.w));
    float m1 = fmaxf(fmaxf(acc1[0]*sc.x, acc1[1]*sc.y),
                     fmaxf(acc1[2]*sc.z, acc1[3]*sc.w));
    m0 = fmaxf(m0, __shfl_xor(m0,16)); m0 = fmaxf(m0, __shfl_xor(m0,32));
    m1 = fmaxf(m1, __shfl_xor(m1,16)); m1 = fmaxf(m1, __shfl_xor(m1,32));
    tm0[t] = m0; tm1[t] = m1;
  }

  if (lane < 16) {
    int q0 = w*32 + lane, q1 = q0 + 16;
    float4 a0 = {tm0[0],tm0[1],tm0[2],tm0[3]};
    float4 a1 = {tm0[4],tm0[5],tm0[6],tm0[7]};
    float4 b0 = {tm1[0],tm1[1],tm1[2],tm1[3]};
    float4 b1 = {tm1[4],tm1[5],tm1[6],tm1[7]};
    float4* p0 = reinterpret_cast<float4*>(&tmax[(size_t)q0*NCHK + blk*8]);
    float4* p1 = reinterpret_cast<float4*>(&tmax[(size_t)q1*NCHK + blk*8]);
    p0[0] = a0; p0[1] = a1;
    p1[0] = b0; p1[1] = b1;
  }
}

// grid 256 (1/query), block 512 (8 waves). Normalizes its own query row,
// then: m5a over chunk maxima -> select chunks >= m5a - MARGIN -> exact f32
// rescore -> exact top-5 + gather. (Unchanged from R10 — proven.)
__global__ __launch_bounds__(512) void select_rescore2(
    const float* __restrict__ tmax, const float* __restrict__ keys,
    const float* __restrict__ query, const int* __restrict__ ts,
    const int* __restrict__ gstep, const float* __restrict__ values,
    float* __restrict__ out) {
  int q = blockIdx.x, tid = threadIdx.x;
  int w = tid >> 6, lane = tid & 63;
  int gstep0 = gstep[0];

  __shared__ float qrow[FEAT];
  if (tid < 16) {
    int d0 = tid * 8;
    const float4* src = reinterpret_cast<const float4*>(query + (size_t)q*FEAT + d0);
    float4 v0 = src[0], v1 = src[1];
    float ss = v0.x*v0.x + v0.y*v0.y + v0.z*v0.z + v0.w*v0.w
             + v1.x*v1.x + v1.y*v1.y + v1.z*v1.z + v1.w*v1.w;
    ss += __shfl_xor(ss,1); ss += __shfl_xor(ss,2);
    ss += __shfl_xor(ss,4); ss += __shfl_xor(ss,8);
    float inv = 1.0f / fmaxf(sqrtf(ss), 1e-12f);
    v0.x*=inv; v0.y*=inv; v0.z*=inv; v0.w*=inv;
    v1.x*=inv; v1.y*=inv; v1.z*=inv; v1.w*=inv;
    float4* dst = reinterpret_cast<float4*>(qrow + d0);
    dst[0] = v0; dst[1] = v1;
  }
  __syncthreads();

  float cs[SCPT]; int ci[SCPT];
  float s5[5] = {-INFINITY,-INFINITY,-INFINITY,-INFINITY,-INFINITY};
  int   i5[5] = {0x7fffffff,0x7fffffff,0x7fffffff,0x7fffffff,0x7fffffff};
  #pragma unroll
  for (int j = 0; j < SCPT; ++j) {
    int c = tid + j*512;
    if (c < NCHK) { cs[j] = tmax[(size_t)q*NCHK + c]; ci[j] = c; }
    else { cs[j] = -INFINITY; ci[j] = 0x7fffffff; }
    ins_cmp(cs[j], ci[j], s5, i5);
  }
  #pragma unroll
  for (int off = 1; off < 64; off <<= 1) {
    float ps[5]; int pi[5];
    #pragma unroll
    for (int j=0;j<5;++j){ ps[j]=__shfl_xor(s5[j],off); pi[j]=__shfl_xor(i5[j],off); }
    #pragma unroll
    for (int j=0;j<5;++j) ins_cmp(ps[j], pi[j], s5, i5);
  }
  __shared__ float rS[8][5]; __shared__ int rI[8][5];
  if (lane == 0) {
    #pragma unroll
    for (int j=0;j<5;++j){ rS[w][j]=s5[j]; rI[w][j]=i5[j]; }
  }
  __syncthreads();
  __shared__ float thSh;
  if (tid == 0) {
    float fs[5]; int fi[5];
    #pragma unroll
    for (int j=0;j<5;++j){ fs[j]=rS[0][j]; fi[j]=rI[0][j]; }
    for (int ww = 1; ww < 8; ++ww)
      #pragma unroll
      for (int j=0;j<5;++j) ins_cmp(rS[ww][j], rI[ww][j], fs, fi);
    thSh = fs[4] - MARGIN;     // m5a - margin
  }
  __syncthreads();
  float th = thSh;

  __shared__ int cnt; __shared__ int clist[MAXSEL];
  if (tid == 0) cnt = 0;
  __syncthreads();
  #pragma unroll
  for (int j = 0; j < SCPT; ++j)
    if (cs[j] >= th && ci[j] < NCHK) {
      int p = atomicAdd(&cnt, 1);
      if (p < MAXSEL) clist[p] = ci[j];
    }
  __syncthreads();
  int nsel = cnt < MAXSEL ? cnt : MAXSEL;

  __shared__ float exs[MAXSEL*16];
  for (int s4 = tid; s4 < nsel*64; s4 += 512) {
    int slot = s4 >> 2, part = s4 & 3;
    int key = clist[slot >> 4]*16 + (slot & 15);
    float dot = 0.f, ksq = 0.f;
    if (key < CAP) {
      const float4* kp = reinterpret_cast<const float4*>(keys + (size_t)key*FEAT + part*32);
      const float4* qp = reinterpret_cast<float4*>(qrow) + part*8;
      #pragma unroll
      for (int d = 0; d < 8; ++d) {
        float4 kv = kp[d];
        float4 qv = qp[d];
        dot = fmaf(kv.w,qv.w,fmaf(kv.z,qv.z,fmaf(kv.y,qv.y,fmaf(kv.x,qv.x,dot))));
        ksq = fmaf(kv.w,kv.w,fmaf(kv.z,kv.z,fmaf(kv.y,kv.y,fmaf(kv.x,kv.x,ksq))));
      }
    }
    dot += __shfl_xor(dot,1); dot += __shfl_xor(dot,2);
    ksq += __shfl_xor(ksq,1); ksq += __shfl_xor(ksq,2);
    if (part == 0) {
      float sim = -INFINITY;
      if (key < CAP) {
        float age = (float)(gstep0 - ts[key]);
        sim = dot / fmaxf(sqrtf(ksq), 1e-12f) * powf(0.995f, age);
      }
      exs[slot] = sim;
    }
  }
  __syncthreads();

  float fs5[5] = {-INFINITY,-INFINITY,-INFINITY,-INFINITY,-INFINITY};
  int   fi5[5] = {0x7fffffff,0x7fffffff,0x7fffffff,0x7fffffff,0x7fffffff};
  if (tid < nsel*16) {
    fs5[0] = exs[tid];
    fi5[0] = clist[tid >> 4]*16 + (tid & 15);
  }
  #pragma unroll
  for (int off = 1; off < 64; off <<= 1) {
    float ps[5]; int pi[5];
    #pragma unroll
    for (int j=0;j<5;++j){ ps[j]=__shfl_xor(fs5[j],off); pi[j]=__shfl_xor(fi5[j],off); }
    #pragma unroll
    for (int j=0;j<5;++j) ins_cmp(ps[j], pi[j], fs5, fi5);
  }
  if (lane == 0) {
    #pragma unroll
    for (int j=0;j<5;++j){ rS[w][j]=fs5[j]; rI[w][j]=fi5[j]; }
  }
  __syncthreads();
  __shared__ int wix[K];
  if (tid == 0) {
    float fs[5]; int fi[5];
    #pragma unroll
    for (int j=0;j<5;++j){ fs[j]=rS[0][j]; fi[j]=rI[0][j]; }
    for (int ww = 1; ww < 8; ++ww)
      #pragma unroll
      for (int j=0;j<5;++j) ins_cmp(rS[ww][j], rI[ww][j], fs, fi);
    #pragma unroll
    for (int r = 0; r < K; ++r) {
      out[OUT_SIMS + q*K + r] = fs[r];
      out[OUT_MASK + q*K + r] = (fs[r] >= 0.0f) ? 1.0f : 0.0f;
      out[OUT_IDX  + q*K + r] = (float)fi[r];
      wix[r] = fi[r];
    }
  }
  __syncthreads();
  for (int idx = tid; idx < K*ROWF; idx += 512) {
    int r = idx / ROWF, e = idx - r*ROWF;
    out[(q*K + r)*ROWF + e] = values[(size_t)wix[r]*ROWF + e];
  }
}

extern "C" void kernel_launch(void* const* d_in, const int* in_sizes, int n_in,
                              void* d_out, int out_size, void* d_ws, size_t ws_size,
                              hipStream_t stream) {
  const float* query  = (const float*)d_in[0];
  const float* keys   = (const float*)d_in[1];
  const float* values = (const float*)d_in[2];
  const int*   ts     = (const int*)d_in[3];
  const int*   gstep  = (const int*)d_in[4];

  float* out   = (float*)d_out;
  float* wsf   = (float*)d_ws;
  float* scale = wsf + WS_SCALE;
  uint4* qF    = (uint4*)(wsf + WS_QF);
  float* tmax  = wsf + WS_TMAX;

  prep<<<16 + NKB, 256, 0, stream>>>(query, keys, ts, gstep, qF, scale);
  gemm_max3<<<NBLK2, 512, 0, stream>>>(keys, scale, qF, tmax);
  select_rescore2<<<BATCH, 512, 0, stream>>>(tmax, keys, query, ts, gstep, values, out);
}